// Round 5
// baseline (386.549 us; speedup 1.0000x reference)
//
#include <hip/hip_runtime.h>

#define INPUT 32
#define HIDDEN 64
#define BATCH 4096
#define SEQ 256

typedef __attribute__((ext_vector_type(8))) short bf16x8;   // 8 bf16 (4 VGPRs)
typedef __attribute__((ext_vector_type(4))) float floatx4;  // 4 fp32

#define MFMA(a, b, c) __builtin_amdgcn_mfma_f32_16x16x32_bf16((a), (b), (c), 0, 0, 0)

// LDS-only barrier: wait LDS ops, leave global loads in flight.
#define LDS_BARRIER() asm volatile("s_waitcnt lgkmcnt(0)\n\ts_barrier" ::: "memory")

// Register pin: zero-instruction volatile asm that (a) forces the loaded
// value to materialize into VGPRs HERE (load can't be sunk past it: the pin
// reads it), (b) makes consumers read an opaque asm output (can't be
// rematerialized as a later re-load), (c) being volatile, won't be
// reordered across the per-step volatile LDS_BARRIERs. This is the fix for
// the collapsed x-prefetch: r12/r16 VGPR counts (68/88) prove the compiler
// sank the ring loads to their use point, exposing L2/HBM latency inside
// every serial step.
#define PINF4(v) asm volatile("" : "+v"((v).x), "+v"((v).y), "+v"((v).z), "+v"((v).w))

// RNE f32->bf16 scalar (setup-only).
__device__ __forceinline__ unsigned short f2bf(float f) {
    unsigned u = __float_as_uint(f);
    u += 0x7fffu + ((u >> 16) & 1u);
    return (unsigned short)(u >> 16);
}
__device__ __forceinline__ float bf2f(unsigned short b) {
    return __uint_as_float(((unsigned)b) << 16);
}
__device__ __forceinline__ void split8(const float f[8], bf16x8& hi, bf16x8& lo) {
#pragma unroll
    for (int j = 0; j < 8; ++j) {
        unsigned short h = f2bf(f[j]);
        hi[j] = (short)h;
        lo[j] = (short)f2bf(f[j] - bf2f(h));
    }
}

// Truncation split of a pair -> packed hi/lo words (6 VALU). Used for x.
__device__ __forceinline__ void packpair(float f0, float f1, unsigned& hw, unsigned& lw) {
    unsigned b0 = __float_as_uint(f0), b1 = __float_as_uint(f1);
    float h0 = __uint_as_float(b0 & 0xffff0000u);
    float h1 = __uint_as_float(b1 & 0xffff0000u);
    float l0 = f0 - h0, l1 = f1 - h1;
    hw = __builtin_amdgcn_perm(b1, b0, 0x07060302u);
    lw = __builtin_amdgcn_perm(__float_as_uint(l1), __float_as_uint(l0), 0x07060302u);
}

// RNE pack of a pair (recurrent state: accuracy matters).
__device__ __forceinline__ unsigned pack_rne(float f0, float f1) {
    unsigned r0 = __float_as_uint(f0);
    r0 += 0x7fffu + ((r0 >> 16) & 1u);
    unsigned r1 = __float_as_uint(f1);
    r1 += 0x7fffu + ((r1 >> 16) & 1u);
    return __builtin_amdgcn_perm(r1, r0, 0x07060302u);
}

union FragU { bf16x8 v; unsigned u[4]; };

// Round-17: EXACTLY the r12 kernel (best measured base: 142us/dispatch,
// absmax 0.00390625) + PINF4 register pins on every x-ring load.
// Theory (triangulated r12 VGPR=68, r16 VGPR=88, both < live-state count):
// the compiler sinks the plain-HIP ring loads to their consumption point,
// collapsing the 4-step prefetch distance and putting an L2/HBM-latency
// stall (~300-500cy) inside each of the 256 serial steps. The pin is the
// minimal-diff, hazard-free fix (r13's asm-register loads NaN'd; r14's
// LDS-DMA ring worked but added LDS ops to the barrier'd critical path).
// All math is bit-identical to r12 -> absmax must reproduce 0.00390625.
// Diagnostic: VGPR_Count must rise to >=100, else the pin didn't take.
// Layouts (verified r5-r11): C/D row(m)=4qd+r, col(n)=ln. A: m=ln, k=8qd+j.
//   B: n=ln, k=8qd+j (+32kt). A=W rows (u=16nt+ln), B=state G[k=u][n=batch].
// G in LDS (u16): buf*1024 + kt*512 + ln*32 + slot*8 + j, slot=(qd+(ln>>1))&3.
__global__ __launch_bounds__(256, 1) void rnn_ns2p_kernel(
    const float* __restrict__ x,     // [B, T, 32]
    const float* __restrict__ W_ih,  // [64, 32]
    const float* __restrict__ W_hh,  // [64, 64]
    const float* __restrict__ b_ih,  // [64]
    const float* __restrict__ b_hh,  // [64]
    const float* __restrict__ W_fc,  // [1, 64]
    const float* __restrict__ b_fc,  // [1]
    float* __restrict__ out)         // [B, 1]
{
    const int tid  = threadIdx.x;
    const int nt   = tid >> 6;        // wave id: owns hidden rows [16nt, 16nt+16)
    const int lane = tid & 63;
    const int ln   = lane & 15;
    const int qd   = lane >> 4;
    const int b0   = blockIdx.x * 16;

    __shared__ __align__(16) unsigned short Gs[2048];  // 4 KB: 2 bufs, hi plane
    __shared__ float Ps[64];

    { // zero buffer 0 (h_{-1} = 0)
        unsigned* z = (unsigned*)Gs;
        for (int i = tid; i < 512; i += 256) z[i] = 0u;
    }

    // ---- Static A-operand weights for THIS wave's u-tile ----
    const int mrow = nt * 16 + ln;
    bf16x8 WihH, WihL, WhhH[2], WhhL[2];
    {
        float f[8];
        const float* ri = W_ih + mrow * INPUT + qd * 8;
        *(float4*)&f[0] = *(const float4*)ri;
        *(float4*)&f[4] = *(const float4*)(ri + 4);
        split8(f, WihH, WihL);
        const float* rh = W_hh + mrow * HIDDEN + qd * 8;
#pragma unroll
        for (int kt = 0; kt < 2; ++kt) {
            *(float4*)&f[0] = *(const float4*)(rh + kt * 32);
            *(float4*)&f[4] = *(const float4*)(rh + kt * 32 + 4);
            split8(f, WhhH[kt], WhhL[kt]);
        }
    }
    const int u0 = nt * 16 + qd * 4;   // this lane's 4 output rows
    floatx4 bbv, wfcv;
    {
        float4 bi = *(const float4*)(b_ih + u0);
        float4 bh = *(const float4*)(b_hh + u0);
        bbv[0] = bi.x + bh.x; bbv[1] = bi.y + bh.y;
        bbv[2] = bi.z + bh.z; bbv[3] = bi.w + bh.w;
        float4 wf = *(const float4*)(W_fc + u0);
        wfcv[0] = wf.x; wfcv[1] = wf.y; wfcv[2] = wf.z; wfcv[3] = wf.w;
    }

    // Reader base (B-frag) and writer base (this lane's 4 contiguous u).
    const int rbase = ln * 32 + ((qd + (ln >> 1)) & 3) * 8;
    const int wbase = (u0 >> 5) * 512 + ln * 32 +
                      ((((u0 >> 3) & 3) + (ln >> 1)) & 3) * 8 + (u0 & 7);

    const float* xp = x + (size_t)(b0 + ln) * (SEQ * INPUT) + qd * 8;

    // 4-slot circular x prefetch (slot s holds x[t], t === s mod 4) — PINNED.
    float4 xa[4], xb[4];
#pragma unroll
    for (int i = 0; i < 4; ++i) {
        xa[i] = *(const float4*)(xp + i * INPUT);
        xb[i] = *(const float4*)(xp + i * INPUT + 4);
        PINF4(xa[i]);
        PINF4(xb[i]);
    }

    // ih-projection for t=0.
    floatx4 ihacc;
    {
        FragU xH, xL;
        packpair(xa[0].x, xa[0].y, xH.u[0], xL.u[0]);
        packpair(xa[0].z, xa[0].w, xH.u[1], xL.u[1]);
        packpair(xb[0].x, xb[0].y, xH.u[2], xL.u[2]);
        packpair(xb[0].z, xb[0].w, xH.u[3], xL.u[3]);
        ihacc = MFMA(WihH, xH.v, bbv);
        ihacc = MFMA(WihH, xL.v, ihacc);
        ihacc = MFMA(WihL, xH.v, ihacc);
    }

    __syncthreads();   // zero-init visible

    // Preload G frags for t=0 (buffer 0).
    bf16x8 g0 = *(const bf16x8*)(Gs + rbase);
    bf16x8 g1 = *(const bf16x8*)(Gs + rbase + 512);

    float hv[4];

#pragma unroll 1
    for (int tb = 0; tb < SEQ; tb += 4) {
#pragma unroll
        for (int s = 0; s < 4; ++s) {
            const int t = tb + s;
            // Refill slot s with x[t+4] (3 steps of slack before use) — PINNED.
            const int tn = (t + 4 < SEQ) ? t + 4 : SEQ - 1;
            xa[s] = *(const float4*)(xp + tn * INPUT);
            xb[s] = *(const float4*)(xp + tn * INPUT + 4);
            PINF4(xa[s]);
            PINF4(xb[s]);

            // Off-path: ih-projection for t+1 (covers the g read latency).
            const float4 na = xa[(s + 1) & 3], nb = xb[(s + 1) & 3];
            FragU nxH, nxL;
            packpair(na.x, na.y, nxH.u[0], nxL.u[0]);
            packpair(na.z, na.w, nxH.u[1], nxL.u[1]);
            packpair(nb.x, nb.y, nxH.u[2], nxL.u[2]);
            packpair(nb.z, nb.w, nxH.u[3], nxL.u[3]);
            floatx4 ihn = MFMA(WihH, nxH.v, bbv);
            ihn = MFMA(WihH, nxL.v, ihn);
            ihn = MFMA(WihL, nxH.v, ihn);

            // hh critical path: depth-2 main + parallel depth-2 lo-correction.
            floatx4 a = MFMA(WhhH[0], g0, ihacc);
            a = MFMA(WhhH[1], g1, a);
            floatx4 c = {0.f, 0.f, 0.f, 0.f};
            c = MFMA(WhhL[0], g0, c);
            c = MFMA(WhhL[1], g1, c);

            // tanh of this wave's 4 elements (only ~8 transcendentals/wave).
#pragma unroll
            for (int r = 0; r < 4; ++r) {
                float p = a[r] + c[r];
                float e = __expf(2.0f * p);
                hv[r] = 1.0f - 2.0f * __builtin_amdgcn_rcpf(e + 1.0f);
            }

            // Pack 4 -> 2 u32, ONE ds_write_b64 into the other buffer.
            unsigned w0 = pack_rne(hv[0], hv[1]);
            unsigned w1 = pack_rne(hv[2], hv[3]);
            uint2 wv; wv.x = w0; wv.y = w1;
            *(uint2*)(Gs + (((t & 1) ^ 1) << 10) + wbase) = wv;

            LDS_BARRIER();   // LDS-only drain; x loads stay in flight.

            // Read G for t+1 immediately (latency covered by next off-path).
            const unsigned short* Hr = Gs + (((t & 1) ^ 1) << 10) + rbase;
            g0 = *(const bf16x8*)(Hr);
            g1 = *(const bf16x8*)(Hr + 512);

            ihacc = ihn;
        }
    }

    // ---- Head: out[b] = sum_u wfc[u] * h[u][b] + b_fc ----
    float acc = wfcv[0] * hv[0] + wfcv[1] * hv[1] + wfcv[2] * hv[2] + wfcv[3] * hv[3];
    acc += __shfl_xor(acc, 16, 64);
    acc += __shfl_xor(acc, 32, 64);
    if (qd == 0) Ps[nt * 16 + ln] = acc;
    __syncthreads();
    if (tid < 16)
        out[b0 + tid] = Ps[tid] + Ps[16 + tid] + Ps[32 + tid] + Ps[48 + tid] + b_fc[0];
}

extern "C" void kernel_launch(void* const* d_in, const int* in_sizes, int n_in,
                              void* d_out, int out_size, void* d_ws, size_t ws_size,
                              hipStream_t stream) {
    const float* x    = (const float*)d_in[0];
    const float* W_ih = (const float*)d_in[1];
    const float* W_hh = (const float*)d_in[2];
    const float* b_ih = (const float*)d_in[3];
    const float* b_hh = (const float*)d_in[4];
    const float* W_fc = (const float*)d_in[5];
    const float* b_fc = (const float*)d_in[6];
    float* out = (float*)d_out;

    // 256 tiles of 16 chains; 4 waves/block (one per SIMD), 1 block per CU.
    rnn_ns2p_kernel<<<dim3(BATCH / 16), dim3(256), 0, stream>>>(
        x, W_ih, W_hh, b_ih, b_hh, W_fc, b_fc, out);
}

// Round 6
// 272.074 us; speedup vs baseline: 1.4207x; 1.4207x over previous
//
#include <hip/hip_runtime.h>

#define INPUT 32
#define HIDDEN 64
#define BATCH 4096
#define SEQ 256
#define CHT 32   // timesteps per chunk (LDS ih buffer)

typedef __attribute__((ext_vector_type(8))) short bf16x8;   // 8 bf16 (4 VGPRs)
typedef __attribute__((ext_vector_type(4))) float floatx4;  // 4 fp32

#define MFMA(a, b, c) __builtin_amdgcn_mfma_f32_16x16x32_bf16((a), (b), (c), 0, 0, 0)

// LDS-only barrier: wait LDS ops, leave global loads in flight.
#define LDS_BARRIER() asm volatile("s_waitcnt lgkmcnt(0)\n\ts_barrier" ::: "memory")

// RNE f32->bf16 scalar (setup-only).
__device__ __forceinline__ unsigned short f2bf(float f) {
    unsigned u = __float_as_uint(f);
    u += 0x7fffu + ((u >> 16) & 1u);
    return (unsigned short)(u >> 16);
}
__device__ __forceinline__ float bf2f(unsigned short b) {
    return __uint_as_float(((unsigned)b) << 16);
}
__device__ __forceinline__ void split8(const float f[8], bf16x8& hi, bf16x8& lo) {
#pragma unroll
    for (int j = 0; j < 8; ++j) {
        unsigned short h = f2bf(f[j]);
        hi[j] = (short)h;
        lo[j] = (short)f2bf(f[j] - bf2f(h));
    }
}

// Truncation split of a pair -> packed hi/lo words (6 VALU). Used for x.
__device__ __forceinline__ void packpair(float f0, float f1, unsigned& hw, unsigned& lw) {
    unsigned b0 = __float_as_uint(f0), b1 = __float_as_uint(f1);
    float h0 = __uint_as_float(b0 & 0xffff0000u);
    float h1 = __uint_as_float(b1 & 0xffff0000u);
    float l0 = f0 - h0, l1 = f1 - h1;
    hw = __builtin_amdgcn_perm(b1, b0, 0x07060302u);
    lw = __builtin_amdgcn_perm(__float_as_uint(l1), __float_as_uint(l0), 0x07060302u);
}

// RNE pack of a pair (recurrent state: accuracy matters).
__device__ __forceinline__ unsigned pack_rne(float f0, float f1) {
    unsigned r0 = __float_as_uint(f0);
    r0 += 0x7fffu + ((r0 >> 16) & 1u);
    unsigned r1 = __float_as_uint(f1);
    r1 += 0x7fffu + ((r1 >> 16) & 1u);
    return __builtin_amdgcn_perm(r1, r0, 0x07060302u);
}

union FragU { bf16x8 v; unsigned u[4]; };

__device__ __forceinline__ void pack8(float4 a, float4 b, FragU& H, FragU& L) {
    packpair(a.x, a.y, H.u[0], L.u[0]);
    packpair(a.z, a.w, H.u[1], L.u[1]);
    packpair(b.x, b.y, H.u[2], L.u[2]);
    packpair(b.z, b.w, H.u[3], L.u[3]);
}

// Round-18: two-phase chunked restructure of r12 (best base, 142us/dispatch).
// Evidence: warm replay == cold in ALL rounds -> x-load latency never the
// wall (sunk-load theory dead, r17). r12 per-wave VALU issue = 26% x 4 SIMD
// x 1330cy = ~345cy/step, 2-3x the hh+tanh hand count: the serial loop is
// ISSUE-bound, and ~60% of the issue (x unpack 48 VALU, 3 ihn MFMAs, ring
// copies) is ih-projection work that does NOT depend on h.
// Fix: hoist it. Per 32-step chunk:
//   Phase A (parallel): wave w computes ih = x.W_ih^T + b for t=cb+8w..+8,
//     all 64 hidden rows (3 MFMAs/tile, bit-identical order/math to r12),
//     storing f32 D-layout results into a 128 KiB LDS buffer IH[32][4][256].
//   Phase B (serial, 32 steps): ds_read ihacc (prefetched), 4 hh MFMAs
//     (depth-2 hi + parallel depth-2 lo, bit-identical), tanh, pack_rne,
//     ONE ds_write_b64 exchange, LDS_BARRIER, prefetch g + next ihacc.
// ih detours through f32 LDS (exact) -> h trajectory BIT-IDENTICAL to r12;
// absmax must reproduce 0.00390625.
// Layouts (verified r5-r11): C/D row(m)=4qd+r, col(n)=ln. A: m=ln, k=8qd+j.
//   B: n=ln, k=8qd+j (+32kt). G in LDS (u16): buf*1024 + kt*512 + ln*32 +
//   slot*8 + j, slot=(qd+(ln>>1))&3.
// IH layout: IH[s][mt][(qd*16+ln)*4 + r]  (lane-contiguous 1KB slabs,
//   b128 read/write, conflict-free).
__global__ __launch_bounds__(256, 1) void rnn_2ph_kernel(
    const float* __restrict__ x,     // [B, T, 32]
    const float* __restrict__ W_ih,  // [64, 32]
    const float* __restrict__ W_hh,  // [64, 64]
    const float* __restrict__ b_ih,  // [64]
    const float* __restrict__ b_hh,  // [64]
    const float* __restrict__ W_fc,  // [1, 64]
    const float* __restrict__ b_fc,  // [1]
    float* __restrict__ out)         // [B, 1]
{
    const int tid  = threadIdx.x;
    const int nt   = tid >> 6;        // wave id: owns hidden rows [16nt, 16nt+16)
    const int lane = tid & 63;
    const int ln   = lane & 15;
    const int qd   = lane >> 4;
    const int b0   = blockIdx.x * 16;

    __shared__ __align__(16) float IH[CHT][4][256];     // 128 KiB ih buffer
    __shared__ __align__(16) unsigned short Gs[2048];   // 4 KiB: 2 bufs, hi plane
    __shared__ float Ps[64];

    { // zero G buffer 0 (h_{-1} = 0); visible after first phase-A sync
        unsigned* z = (unsigned*)Gs;
        for (int i = tid; i < 512; i += 256) z[i] = 0u;
    }

    // ---- Static weights ----
    // Full W_ih (all 4 tiles) for phase A; own-tile W_hh for phase B.
    bf16x8 WihH4[4], WihL4[4], WhhH[2], WhhL[2];
    floatx4 bbv4[4];
    {
        float f[8];
#pragma unroll
        for (int mt = 0; mt < 4; ++mt) {
            const float* ri = W_ih + (mt * 16 + ln) * INPUT + qd * 8;
            *(float4*)&f[0] = *(const float4*)ri;
            *(float4*)&f[4] = *(const float4*)(ri + 4);
            split8(f, WihH4[mt], WihL4[mt]);
            float4 bi = *(const float4*)(b_ih + mt * 16 + qd * 4);
            float4 bh = *(const float4*)(b_hh + mt * 16 + qd * 4);
            bbv4[mt][0] = bi.x + bh.x; bbv4[mt][1] = bi.y + bh.y;
            bbv4[mt][2] = bi.z + bh.z; bbv4[mt][3] = bi.w + bh.w;
        }
        const float* rh = W_hh + (nt * 16 + ln) * HIDDEN + qd * 8;
#pragma unroll
        for (int kt = 0; kt < 2; ++kt) {
            *(float4*)&f[0] = *(const float4*)(rh + kt * 32);
            *(float4*)&f[4] = *(const float4*)(rh + kt * 32 + 4);
            split8(f, WhhH[kt], WhhL[kt]);
        }
    }
    const int u0 = nt * 16 + qd * 4;   // this lane's 4 output rows (phase B)
    floatx4 wfcv;
    {
        float4 wf = *(const float4*)(W_fc + u0);
        wfcv[0] = wf.x; wfcv[1] = wf.y; wfcv[2] = wf.z; wfcv[3] = wf.w;
    }

    // Exchange bases (r12, verified): reader (B-frag) and writer.
    const int rbase = ln * 32 + ((qd + (ln >> 1)) & 3) * 8;
    const int wbase = (u0 >> 5) * 512 + ln * 32 +
                      ((((u0 >> 3) & 3) + (ln >> 1)) & 3) * 8 + (u0 & 7);

    const float* xp = x + (size_t)(b0 + ln) * (SEQ * INPUT) + qd * 8;
    const int ihoff = (qd * 16 + ln) * 4;   // this lane's float4 in a slab

    bf16x8 g0, g1;
    floatx4 ihacc;
    float hv[4];

#pragma unroll 1
    for (int cb = 0; cb < SEQ; cb += CHT) {
        // ================= Phase A: ih for t in [cb, cb+CHT) =================
        {
            const int tbase = cb + nt * (CHT / 4);
#pragma unroll
            for (int i = 0; i < CHT / 4; ++i) {
                const int t = tbase + i;
                float4 ra = *(const float4*)(xp + t * INPUT);
                float4 rb = *(const float4*)(xp + t * INPUT + 4);
                FragU H, L;
                pack8(ra, rb, H, L);
#pragma unroll
                for (int mt = 0; mt < 4; ++mt) {
                    floatx4 ih = MFMA(WihH4[mt], H.v, bbv4[mt]);
                    ih = MFMA(WihH4[mt], L.v, ih);
                    ih = MFMA(WihL4[mt], H.v, ih);
                    *(floatx4*)&IH[t - cb][mt][ihoff] = ih;
                }
            }
        }
        __syncthreads();   // IH chunk + (first iter) zero-init visible

        if (cb == 0) {     // initial g = h_{-1} = 0 from G buffer 0
            g0 = *(const bf16x8*)(Gs + rbase);
            g1 = *(const bf16x8*)(Gs + rbase + 512);
        }
        ihacc = *(const floatx4*)&IH[0][nt][ihoff];

        // ================= Phase B: 32 serial steps =================
#pragma unroll 1
        for (int sb = 0; sb < CHT; sb += 2) {
#pragma unroll
            for (int p = 0; p < 2; ++p) {
                const int s = sb + p;   // parity p == s&1 (t = cb+s, cb%32==0)

                // hh critical path: depth-2 main + parallel lo-correction.
                floatx4 a = MFMA(WhhH[0], g0, ihacc);
                a = MFMA(WhhH[1], g1, a);
                floatx4 c = {0.f, 0.f, 0.f, 0.f};
                c = MFMA(WhhL[0], g0, c);
                c = MFMA(WhhL[1], g1, c);

                // tanh of this wave's 4 elements.
#pragma unroll
                for (int r = 0; r < 4; ++r) {
                    float pv = a[r] + c[r];
                    float e = __expf(2.0f * pv);
                    hv[r] = 1.0f - 2.0f * __builtin_amdgcn_rcpf(e + 1.0f);
                }

                // Pack 4 -> 2 u32, ONE ds_write_b64 into the other buffer.
                unsigned w0 = pack_rne(hv[0], hv[1]);
                unsigned w1 = pack_rne(hv[2], hv[3]);
                uint2 wv; wv.x = w0; wv.y = w1;
                *(uint2*)(Gs + ((p ^ 1) << 10) + wbase) = wv;

                LDS_BARRIER();   // publish h_t; nothing else on lgkm queue

                // Prefetch g for t+1 and ihacc for s+1.
                // (s==31: IH read is stale/garbage but overwritten after the
                //  next chunk's phase A + syncthreads — harmless by design.)
                const unsigned short* Hr = Gs + ((p ^ 1) << 10) + rbase;
                g0 = *(const bf16x8*)(Hr);
                g1 = *(const bf16x8*)(Hr + 512);
                ihacc = *(const floatx4*)&IH[(s + 1) & (CHT - 1)][nt][ihoff];
            }
        }
    }

    // ---- Head: out[b] = sum_u wfc[u] * h[u][b] + b_fc ----
    float acc = wfcv[0] * hv[0] + wfcv[1] * hv[1] + wfcv[2] * hv[2] + wfcv[3] * hv[3];
    acc += __shfl_xor(acc, 16, 64);
    acc += __shfl_xor(acc, 32, 64);
    if (qd == 0) Ps[nt * 16 + ln] = acc;
    __syncthreads();
    if (tid < 16)
        out[b0 + tid] = Ps[tid] + Ps[16 + tid] + Ps[32 + tid] + Ps[48 + tid] + b_fc[0];
}

extern "C" void kernel_launch(void* const* d_in, const int* in_sizes, int n_in,
                              void* d_out, int out_size, void* d_ws, size_t ws_size,
                              hipStream_t stream) {
    const float* x    = (const float*)d_in[0];
    const float* W_ih = (const float*)d_in[1];
    const float* W_hh = (const float*)d_in[2];
    const float* b_ih = (const float*)d_in[3];
    const float* b_hh = (const float*)d_in[4];
    const float* W_fc = (const float*)d_in[5];
    const float* b_fc = (const float*)d_in[6];
    float* out = (float*)d_out;

    // 256 tiles of 16 chains; 4 waves/block (one per SIMD), 1 block per CU.
    rnn_2ph_kernel<<<dim3(BATCH / 16), dim3(256), 0, stream>>>(
        x, W_ih, W_hh, b_ih, b_hh, W_fc, b_fc, out);
}